// Round 2
// baseline (293.749 us; speedup 1.0000x reference)
//
#include <hip/hip_runtime.h>
#include <cstdint>
#include <cstddef>

#define D 128
#define P_DROP 0.1f
#define INV_KEEP (1.0f / 0.9f)
#define BN_EPS 1e-5f

// ---------------- init: zero hist / bn accumulators ----------------
__global__ void k_init(int* __restrict__ hist, float* __restrict__ bnacc, int N) {
    int i = blockIdx.x * blockDim.x + threadIdx.x;
    if (i < N) hist[i] = 0;
    if (i < 256) bnacc[i] = 0.f;
}

// ---------------- histogram of dst (in-degree, excl. self loop) ----------------
__global__ void k_hist(const int* __restrict__ dst, int* __restrict__ hist, int E) {
    int i = blockIdx.x * blockDim.x + threadIdx.x;
    if (i < E) atomicAdd(&hist[dst[i]], 1);
}

// ---------------- 2-level exclusive scan ----------------
__global__ void k_scanA(const int* __restrict__ hist, int* __restrict__ tmp,
                        int* __restrict__ blocksum, int N) {
    __shared__ int sd[256];
    int tid = threadIdx.x;
    int i = blockIdx.x * 256 + tid;
    sd[tid] = (i < N) ? hist[i] : 0;
    __syncthreads();
    for (int o = 1; o < 256; o <<= 1) {
        int t = (tid >= o) ? sd[tid - o] : 0;
        __syncthreads();
        sd[tid] += t;
        __syncthreads();
    }
    tmp[i] = sd[tid];                       // inclusive within block
    if (tid == 255) blocksum[blockIdx.x] = sd[255];
}

__global__ void k_scanB(const int* __restrict__ blocksum, int* __restrict__ blockoff,
                        int NBLK) {
    __shared__ int sd[256];
    int tid = threadIdx.x;
    int v = (tid < NBLK) ? blocksum[tid] : 0;
    sd[tid] = v;
    __syncthreads();
    for (int o = 1; o < 256; o <<= 1) {
        int t = (tid >= o) ? sd[tid - o] : 0;
        __syncthreads();
        sd[tid] += t;
        __syncthreads();
    }
    if (tid < NBLK) blockoff[tid] = sd[tid] - v;   // exclusive
}

// off[i+1] = inclusive scan; cursor[i] = exclusive scan (live write index for place)
__global__ void k_scanC(const int* __restrict__ tmp, const int* __restrict__ blockoff,
                        const int* __restrict__ hist,
                        int* __restrict__ off, int* __restrict__ cursor, int N) {
    int i = blockIdx.x * 256 + threadIdx.x;
    if (i < N) {
        int incl = tmp[i] + blockoff[blockIdx.x];
        off[i + 1] = incl;
        cursor[i] = incl - hist[i];
    }
    if (i == 0) off[0] = 0;
}

// ---------------- CSR placement (cursor holds absolute write index) ----------------
__global__ void k_place(const int* __restrict__ src, const int* __restrict__ dst,
                        int* __restrict__ cursor, int* __restrict__ ebuf, int E) {
    int i = blockIdx.x * blockDim.x + threadIdx.x;
    if (i < E) {
        int p = atomicAdd(&cursor[dst[i]], 1);
        ebuf[p] = src[i];
    }
}

// ---------------- GEMM xw' = (x @ W) * rsqrt(deg) ----------------
__global__ __launch_bounds__(256) void k_gemm(
    const float* __restrict__ x, const float* __restrict__ w,
    const int* __restrict__ hist, float* __restrict__ xwp,
    float* __restrict__ dinv, int N) {
    __shared__ float wl[32][D];     // 16 KB
    __shared__ float xl[32][68];    // 8.5 KB
    int tid = threadIdx.x;
    int tx = tid & 15, ty = tid >> 4;
    int row0 = blockIdx.x * 64;
    float acc[4][8];
#pragma unroll
    for (int r = 0; r < 4; ++r)
#pragma unroll
        for (int c = 0; c < 8; ++c) acc[r][c] = 0.f;

    for (int k0 = 0; k0 < D; k0 += 32) {
#pragma unroll
        for (int i = 0; i < 4; ++i) {
            int f = tid + i * 256;
            int kk = f >> 5, cc = (f & 31) << 2;
            *(float4*)&wl[kk][cc] = *(const float4*)&w[(size_t)(k0 + kk) * D + cc];
        }
#pragma unroll
        for (int i = 0; i < 2; ++i) {
            int f = tid + i * 256;
            int r = f >> 3, kk = (f & 7) << 2;
            int row = row0 + r;
            float4 v = (row < N) ? *(const float4*)&x[(size_t)row * D + k0 + kk]
                                 : make_float4(0.f, 0.f, 0.f, 0.f);
            xl[kk + 0][r] = v.x; xl[kk + 1][r] = v.y;
            xl[kk + 2][r] = v.z; xl[kk + 3][r] = v.w;
        }
        __syncthreads();
#pragma unroll
        for (int k = 0; k < 32; ++k) {
            float4 xa = *(float4*)&xl[k][ty * 4];
            float4 w0 = *(float4*)&wl[k][tx * 8];
            float4 w1 = *(float4*)&wl[k][tx * 8 + 4];
            float xr[4] = {xa.x, xa.y, xa.z, xa.w};
#pragma unroll
            for (int r = 0; r < 4; ++r) {
                acc[r][0] = fmaf(xr[r], w0.x, acc[r][0]);
                acc[r][1] = fmaf(xr[r], w0.y, acc[r][1]);
                acc[r][2] = fmaf(xr[r], w0.z, acc[r][2]);
                acc[r][3] = fmaf(xr[r], w0.w, acc[r][3]);
                acc[r][4] = fmaf(xr[r], w1.x, acc[r][4]);
                acc[r][5] = fmaf(xr[r], w1.y, acc[r][5]);
                acc[r][6] = fmaf(xr[r], w1.z, acc[r][6]);
                acc[r][7] = fmaf(xr[r], w1.w, acc[r][7]);
            }
        }
        __syncthreads();
    }
#pragma unroll
    for (int r = 0; r < 4; ++r) {
        int row = row0 + ty * 4 + r;
        if (row < N) {
            float dv = rsqrtf((float)(hist[row] + 1));  // deg includes self loop
            if (tx == 0) dinv[row] = dv;
            float4 o0 = make_float4(acc[r][0] * dv, acc[r][1] * dv,
                                    acc[r][2] * dv, acc[r][3] * dv);
            float4 o1 = make_float4(acc[r][4] * dv, acc[r][5] * dv,
                                    acc[r][6] * dv, acc[r][7] * dv);
            *(float4*)&xwp[(size_t)row * D + tx * 8] = o0;
            *(float4*)&xwp[(size_t)row * D + tx * 8 + 4] = o1;
        }
    }
}

// ---------------- gather-aggregate + bias + ReLU + BN partial sums ----------------
// one wave per node; half-wave per edge stream; lane covers 4 cols (float4).
// lanes 0-31: even edges + self row; lanes 32-63: odd edges. Merge via shfl.
__global__ __launch_bounds__(256) void k_aggregate(
    const float* __restrict__ xwp, const float* __restrict__ dinv,
    const int* __restrict__ off, const int* __restrict__ ebuf,
    const float* __restrict__ bias, float* __restrict__ y,
    float* __restrict__ bnacc, int N, int NW) {
    int tid = threadIdx.x;
    int lane = tid & 63;
    int wv = tid >> 6;
    int half = lane >> 5;          // 0 / 1
    int c4 = lane & 31;            // float4 column index within row
    int wglob = blockIdx.x * 4 + wv;
    float4 b4 = ((const float4*)bias)[c4];
    float hm = (half == 0) ? 1.f : 0.f;
    float ps0 = 0.f, ps1 = 0.f, ps2 = 0.f, ps3 = 0.f;
    float pq0 = 0.f, pq1 = 0.f, pq2 = 0.f, pq3 = 0.f;

    for (int node = wglob; node < N; node += NW) {
        int s0 = __builtin_amdgcn_readfirstlane(off[node]);
        int s1 = __builtin_amdgcn_readfirstlane(off[node + 1]);
        // self row: counted once (low half only)
        float4 sv = ((const float4*)(xwp + (size_t)node * D))[c4];
        float ax = sv.x * hm, ay = sv.y * hm, az = sv.z * hm, aw = sv.w * hm;
        int e = s0;
        for (; e + 8 <= s1; e += 8) {            // 8 edges in flight (4 x 1KB loads)
            int i0 = ebuf[e + half];
            int i1 = ebuf[e + 2 + half];
            int i2 = ebuf[e + 4 + half];
            int i3 = ebuf[e + 6 + half];
            float4 v0 = ((const float4*)(xwp + (size_t)i0 * D))[c4];
            float4 v1 = ((const float4*)(xwp + (size_t)i1 * D))[c4];
            float4 v2 = ((const float4*)(xwp + (size_t)i2 * D))[c4];
            float4 v3 = ((const float4*)(xwp + (size_t)i3 * D))[c4];
            ax += (v0.x + v1.x) + (v2.x + v3.x);
            ay += (v0.y + v1.y) + (v2.y + v3.y);
            az += (v0.z + v1.z) + (v2.z + v3.z);
            aw += (v0.w + v1.w) + (v2.w + v3.w);
        }
        for (; e + 2 <= s1; e += 2) {            // pair tail
            int i0 = ebuf[e + half];
            float4 v0 = ((const float4*)(xwp + (size_t)i0 * D))[c4];
            ax += v0.x; ay += v0.y; az += v0.z; aw += v0.w;
        }
        if (e < s1) {                            // single tail (low half only)
            int i0 = ebuf[e];
            float4 v0 = ((const float4*)(xwp + (size_t)i0 * D))[c4];
            ax += v0.x * hm; ay += v0.y * hm; az += v0.z * hm; aw += v0.w * hm;
        }
        // merge odd-edge stream (high half) into low half
        ax += __shfl_down(ax, 32);
        ay += __shfl_down(ay, 32);
        az += __shfl_down(az, 32);
        aw += __shfl_down(aw, 32);
        if (half == 0) {
            float dv = dinv[node];
            float y0 = fmaxf(fmaf(ax, dv, b4.x), 0.f);
            float y1 = fmaxf(fmaf(ay, dv, b4.y), 0.f);
            float y2 = fmaxf(fmaf(az, dv, b4.z), 0.f);
            float y3 = fmaxf(fmaf(aw, dv, b4.w), 0.f);
            ((float4*)(y + (size_t)node * D))[c4] = make_float4(y0, y1, y2, y3);
            ps0 += y0; ps1 += y1; ps2 += y2; ps3 += y3;
            pq0 += y0 * y0; pq1 += y1 * y1; pq2 += y2 * y2; pq3 += y3 * y3;
        }
    }

    __shared__ float red_s[4][128];
    __shared__ float red_q[4][128];
    if (half == 0) {
        red_s[wv][c4 * 4 + 0] = ps0; red_s[wv][c4 * 4 + 1] = ps1;
        red_s[wv][c4 * 4 + 2] = ps2; red_s[wv][c4 * 4 + 3] = ps3;
        red_q[wv][c4 * 4 + 0] = pq0; red_q[wv][c4 * 4 + 1] = pq1;
        red_q[wv][c4 * 4 + 2] = pq2; red_q[wv][c4 * 4 + 3] = pq3;
    }
    __syncthreads();
    if (tid < 128) {
        float s = red_s[0][tid] + red_s[1][tid] + red_s[2][tid] + red_s[3][tid];
        atomicAdd(&bnacc[tid], s);
    } else {
        int c = tid - 128;
        float q = red_q[0][c] + red_q[1][c] + red_q[2][c] + red_q[3][c];
        atomicAdd(&bnacc[128 + c], q);
    }
}

// ---------------- BN finalize: per-column scale/shift ----------------
__global__ void k_bnfinal(const float* __restrict__ bnacc, const float* __restrict__ gamma,
                          const float* __restrict__ beta, float* __restrict__ scsh, int N) {
    int c = threadIdx.x;
    if (c < 128) {
        float invN = 1.0f / (float)N;
        float mean = bnacc[c] * invN;
        float var = bnacc[128 + c] * invN - mean * mean;
        var = fmaxf(var, 0.f);
        float sc = gamma[c] * rsqrtf(var + BN_EPS);
        scsh[c] = sc;
        scsh[128 + c] = beta[c] - mean * sc;
    }
}

// ---------------- normalize + dropout, in place on d_out ----------------
__global__ __launch_bounds__(256) void k_finalize(
    float* __restrict__ out, const float* __restrict__ u,
    const float* __restrict__ scsh, int total4) {
    int i = blockIdx.x * 256 + threadIdx.x;
    if (i >= total4) return;
    float4 v = ((const float4*)out)[i];
    float4 uu = ((const float4*)u)[i];
    int c = (i & 31) * 4;
    float s0 = scsh[c], s1 = scsh[c + 1], s2 = scsh[c + 2], s3 = scsh[c + 3];
    float h0 = scsh[128 + c], h1 = scsh[128 + c + 1];
    float h2 = scsh[128 + c + 2], h3 = scsh[128 + c + 3];
    v.x = fmaf(v.x, s0, h0) * (uu.x > P_DROP ? INV_KEEP : 0.f);
    v.y = fmaf(v.y, s1, h1) * (uu.y > P_DROP ? INV_KEEP : 0.f);
    v.z = fmaf(v.z, s2, h2) * (uu.z > P_DROP ? INV_KEEP : 0.f);
    v.w = fmaf(v.w, s3, h3) * (uu.w > P_DROP ? INV_KEEP : 0.f);
    ((float4*)out)[i] = v;
}

extern "C" void kernel_launch(void* const* d_in, const int* in_sizes, int n_in,
                              void* d_out, int out_size, void* d_ws, size_t ws_size,
                              hipStream_t stream) {
    const float* x      = (const float*)d_in[0];
    const float* weight = (const float*)d_in[1];
    const float* bias   = (const float*)d_in[2];
    const float* gamma  = (const float*)d_in[3];
    const float* beta   = (const float*)d_in[4];
    const float* du     = (const float*)d_in[5];
    const int*   eidx   = (const int*)d_in[6];
    float* out = (float*)d_out;

    const int N = in_sizes[0] / D;      // 50000
    const int E = in_sizes[6] / 2;      // 600000
    const int* esrc = eidx;
    const int* edst = eidx + E;

    char* p = (char*)d_ws;
    auto alloc = [&](size_t bytes) {
        char* q = p;
        p += (bytes + 255) & ~(size_t)255;
        return q;
    };
    float* xwp      = (float*)alloc((size_t)N * D * sizeof(float));
    int*   hist     = (int*)alloc((size_t)N * sizeof(int));
    int*   cursor   = (int*)alloc((size_t)N * sizeof(int));
    int*   off      = (int*)alloc((size_t)(N + 1) * sizeof(int));
    const int NBLK = (N + 255) / 256;   // 196 (<=256 required by scanB)
    int*   tmp      = (int*)alloc((size_t)NBLK * 256 * sizeof(int));
    int*   blocksum = (int*)alloc((size_t)NBLK * sizeof(int));
    int*   blockoff = (int*)alloc((size_t)NBLK * sizeof(int));
    int*   ebuf     = (int*)alloc((size_t)E * sizeof(int));
    float* dinv     = (float*)alloc((size_t)N * sizeof(float));
    float* bnacc    = (float*)alloc(256 * sizeof(float));
    float* scsh     = (float*)alloc(256 * sizeof(float));

    const int EB = (E + 255) / 256;
    hipLaunchKernelGGL(k_init, dim3(NBLK), dim3(256), 0, stream, hist, bnacc, N);
    hipLaunchKernelGGL(k_hist, dim3(EB), dim3(256), 0, stream, edst, hist, E);
    hipLaunchKernelGGL(k_scanA, dim3(NBLK), dim3(256), 0, stream, hist, tmp, blocksum, N);
    hipLaunchKernelGGL(k_scanB, dim3(1), dim3(256), 0, stream, blocksum, blockoff, NBLK);
    hipLaunchKernelGGL(k_scanC, dim3(NBLK), dim3(256), 0, stream, tmp, blockoff, hist, off, cursor, N);
    hipLaunchKernelGGL(k_place, dim3(EB), dim3(256), 0, stream, esrc, edst, cursor, ebuf, E);
    hipLaunchKernelGGL(k_gemm, dim3((N + 63) / 64), dim3(256), 0, stream,
                       x, weight, hist, xwp, dinv, N);
    const int AGG_BLOCKS = 2048;
    hipLaunchKernelGGL(k_aggregate, dim3(AGG_BLOCKS), dim3(256), 0, stream,
                       xwp, dinv, off, ebuf, bias, out, bnacc, N, AGG_BLOCKS * 4);
    hipLaunchKernelGGL(k_bnfinal, dim3(1), dim3(128), 0, stream, bnacc, gamma, beta, scsh, N);
    const int total4 = N * (D / 4);
    hipLaunchKernelGGL(k_finalize, dim3((total4 + 255) / 256), dim3(256), 0, stream,
                       out, du, scsh, total4);
}

// Round 3
// 280.409 us; speedup vs baseline: 1.0476x; 1.0476x over previous
//
#include <hip/hip_runtime.h>
#include <cstdint>
#include <cstddef>

#define D 128
#define P_DROP 0.1f
#define INV_KEEP (1.0f / 0.9f)
#define BN_EPS 1e-5f

// round-to-nearest-even f32 -> bf16 bits (inputs are finite, no NaN handling)
__device__ __forceinline__ unsigned f2bf(float f) {
    unsigned u = __float_as_uint(f);
    return (u + 0x7fffu + ((u >> 16) & 1u)) >> 16;
}

// ---------------- init: zero hist / bn accumulators ----------------
__global__ void k_init(int* __restrict__ hist, float* __restrict__ bnacc, int N) {
    int i = blockIdx.x * blockDim.x + threadIdx.x;
    if (i < N) hist[i] = 0;
    if (i < 256) bnacc[i] = 0.f;
}

// ---------------- histogram of dst (in-degree, excl. self loop) ----------------
__global__ void k_hist(const int* __restrict__ dst, int* __restrict__ hist, int E) {
    int i = blockIdx.x * blockDim.x + threadIdx.x;
    if (i < E) atomicAdd(&hist[dst[i]], 1);
}

// ---------------- 2-level exclusive scan ----------------
__global__ void k_scanA(const int* __restrict__ hist, int* __restrict__ tmp,
                        int* __restrict__ blocksum, int N) {
    __shared__ int sd[256];
    int tid = threadIdx.x;
    int i = blockIdx.x * 256 + tid;
    sd[tid] = (i < N) ? hist[i] : 0;
    __syncthreads();
    for (int o = 1; o < 256; o <<= 1) {
        int t = (tid >= o) ? sd[tid - o] : 0;
        __syncthreads();
        sd[tid] += t;
        __syncthreads();
    }
    tmp[i] = sd[tid];                       // inclusive within block
    if (tid == 255) blocksum[blockIdx.x] = sd[255];
}

__global__ void k_scanB(const int* __restrict__ blocksum, int* __restrict__ blockoff,
                        int NBLK) {
    __shared__ int sd[256];
    int tid = threadIdx.x;
    int v = (tid < NBLK) ? blocksum[tid] : 0;
    sd[tid] = v;
    __syncthreads();
    for (int o = 1; o < 256; o <<= 1) {
        int t = (tid >= o) ? sd[tid - o] : 0;
        __syncthreads();
        sd[tid] += t;
        __syncthreads();
    }
    if (tid < NBLK) blockoff[tid] = sd[tid] - v;   // exclusive
}

// off[i+1] = inclusive scan; cursor[i] = exclusive scan (live write index for place)
__global__ void k_scanC(const int* __restrict__ tmp, const int* __restrict__ blockoff,
                        const int* __restrict__ hist,
                        int* __restrict__ off, int* __restrict__ cursor, int N) {
    int i = blockIdx.x * 256 + threadIdx.x;
    if (i < N) {
        int incl = tmp[i] + blockoff[blockIdx.x];
        off[i + 1] = incl;
        cursor[i] = incl - hist[i];
    }
    if (i == 0) off[0] = 0;
}

// ---------------- CSR placement (cursor holds absolute write index) ----------------
__global__ void k_place(const int* __restrict__ src, const int* __restrict__ dst,
                        int* __restrict__ cursor, int* __restrict__ ebuf, int E) {
    int i = blockIdx.x * blockDim.x + threadIdx.x;
    if (i < E) {
        int p = atomicAdd(&cursor[dst[i]], 1);
        ebuf[p] = src[i];
    }
}

// ---------------- GEMM xwb = bf16((x @ W) * rsqrt(deg)) ----------------
__global__ __launch_bounds__(256) void k_gemm(
    const float* __restrict__ x, const float* __restrict__ w,
    const int* __restrict__ hist, unsigned short* __restrict__ xwb,
    float* __restrict__ dinv, int N) {
    __shared__ float wl[32][D];     // 16 KB
    __shared__ float xl[32][68];    // 8.5 KB
    int tid = threadIdx.x;
    int tx = tid & 15, ty = tid >> 4;
    int row0 = blockIdx.x * 64;
    float acc[4][8];
#pragma unroll
    for (int r = 0; r < 4; ++r)
#pragma unroll
        for (int c = 0; c < 8; ++c) acc[r][c] = 0.f;

    for (int k0 = 0; k0 < D; k0 += 32) {
#pragma unroll
        for (int i = 0; i < 4; ++i) {
            int f = tid + i * 256;
            int kk = f >> 5, cc = (f & 31) << 2;
            *(float4*)&wl[kk][cc] = *(const float4*)&w[(size_t)(k0 + kk) * D + cc];
        }
#pragma unroll
        for (int i = 0; i < 2; ++i) {
            int f = tid + i * 256;
            int r = f >> 3, kk = (f & 7) << 2;
            int row = row0 + r;
            float4 v = (row < N) ? *(const float4*)&x[(size_t)row * D + k0 + kk]
                                 : make_float4(0.f, 0.f, 0.f, 0.f);
            xl[kk + 0][r] = v.x; xl[kk + 1][r] = v.y;
            xl[kk + 2][r] = v.z; xl[kk + 3][r] = v.w;
        }
        __syncthreads();
#pragma unroll
        for (int k = 0; k < 32; ++k) {
            float4 xa = *(float4*)&xl[k][ty * 4];
            float4 w0 = *(float4*)&wl[k][tx * 8];
            float4 w1 = *(float4*)&wl[k][tx * 8 + 4];
            float xr[4] = {xa.x, xa.y, xa.z, xa.w};
#pragma unroll
            for (int r = 0; r < 4; ++r) {
                acc[r][0] = fmaf(xr[r], w0.x, acc[r][0]);
                acc[r][1] = fmaf(xr[r], w0.y, acc[r][1]);
                acc[r][2] = fmaf(xr[r], w0.z, acc[r][2]);
                acc[r][3] = fmaf(xr[r], w0.w, acc[r][3]);
                acc[r][4] = fmaf(xr[r], w1.x, acc[r][4]);
                acc[r][5] = fmaf(xr[r], w1.y, acc[r][5]);
                acc[r][6] = fmaf(xr[r], w1.z, acc[r][6]);
                acc[r][7] = fmaf(xr[r], w1.w, acc[r][7]);
            }
        }
        __syncthreads();
    }
#pragma unroll
    for (int r = 0; r < 4; ++r) {
        int row = row0 + ty * 4 + r;
        if (row < N) {
            float dv = rsqrtf((float)(hist[row] + 1));  // deg includes self loop
            if (tx == 0) dinv[row] = dv;
            unsigned q0 = f2bf(acc[r][0] * dv) | (f2bf(acc[r][1] * dv) << 16);
            unsigned q1 = f2bf(acc[r][2] * dv) | (f2bf(acc[r][3] * dv) << 16);
            unsigned q2 = f2bf(acc[r][4] * dv) | (f2bf(acc[r][5] * dv) << 16);
            unsigned q3 = f2bf(acc[r][6] * dv) | (f2bf(acc[r][7] * dv) << 16);
            *(uint4*)&xwb[(size_t)row * D + tx * 8] = make_uint4(q0, q1, q2, q3);
        }
    }
}

// ---------------- gather-aggregate (bf16 rows) + bias + ReLU + BN partials ----------------
// one wave per node; half-wave per edge stream; lane covers 4 cols (uint2 = 4 bf16).
__global__ __launch_bounds__(256) void k_aggregate(
    const unsigned short* __restrict__ xwb, const float* __restrict__ dinv,
    const int* __restrict__ off, const int* __restrict__ ebuf,
    const float* __restrict__ bias, float* __restrict__ y,
    float* __restrict__ bnacc, int N, int NW) {
    int tid = threadIdx.x;
    int lane = tid & 63;
    int wv = tid >> 6;
    int half = lane >> 5;          // 0 / 1
    int c4 = lane & 31;            // float4-column index within row (cols 4*c4..+3)
    int wglob = blockIdx.x * 4 + wv;
    float4 b4 = ((const float4*)bias)[c4];
    float hm = (half == 0) ? 1.f : 0.f;
    float ps0 = 0.f, ps1 = 0.f, ps2 = 0.f, ps3 = 0.f;
    float pq0 = 0.f, pq1 = 0.f, pq2 = 0.f, pq3 = 0.f;

    for (int node = wglob; node < N; node += NW) {
        int s0 = __builtin_amdgcn_readfirstlane(off[node]);
        int s1 = __builtin_amdgcn_readfirstlane(off[node + 1]);
        // self row: counted once (low half only)
        uint2 sr = ((const uint2*)(xwb + (size_t)node * D))[c4];
        float ax = __uint_as_float(sr.x << 16) * hm;
        float ay = __uint_as_float(sr.x & 0xffff0000u) * hm;
        float az = __uint_as_float(sr.y << 16) * hm;
        float aw = __uint_as_float(sr.y & 0xffff0000u) * hm;
        int e = s0;
        for (; e + 8 <= s1; e += 8) {            // 8 edges in flight (4 x 512B loads)
            int i0 = ebuf[e + half];
            int i1 = ebuf[e + 2 + half];
            int i2 = ebuf[e + 4 + half];
            int i3 = ebuf[e + 6 + half];
            uint2 v0 = ((const uint2*)(xwb + (size_t)i0 * D))[c4];
            uint2 v1 = ((const uint2*)(xwb + (size_t)i1 * D))[c4];
            uint2 v2 = ((const uint2*)(xwb + (size_t)i2 * D))[c4];
            uint2 v3 = ((const uint2*)(xwb + (size_t)i3 * D))[c4];
            ax += __uint_as_float(v0.x << 16) + __uint_as_float(v1.x << 16)
                + __uint_as_float(v2.x << 16) + __uint_as_float(v3.x << 16);
            ay += __uint_as_float(v0.x & 0xffff0000u) + __uint_as_float(v1.x & 0xffff0000u)
                + __uint_as_float(v2.x & 0xffff0000u) + __uint_as_float(v3.x & 0xffff0000u);
            az += __uint_as_float(v0.y << 16) + __uint_as_float(v1.y << 16)
                + __uint_as_float(v2.y << 16) + __uint_as_float(v3.y << 16);
            aw += __uint_as_float(v0.y & 0xffff0000u) + __uint_as_float(v1.y & 0xffff0000u)
                + __uint_as_float(v2.y & 0xffff0000u) + __uint_as_float(v3.y & 0xffff0000u);
        }
        for (; e + 2 <= s1; e += 2) {            // pair tail
            int i0 = ebuf[e + half];
            uint2 v0 = ((const uint2*)(xwb + (size_t)i0 * D))[c4];
            ax += __uint_as_float(v0.x << 16);
            ay += __uint_as_float(v0.x & 0xffff0000u);
            az += __uint_as_float(v0.y << 16);
            aw += __uint_as_float(v0.y & 0xffff0000u);
        }
        if (e < s1) {                            // single tail (low half only)
            int i0 = ebuf[e];
            uint2 v0 = ((const uint2*)(xwb + (size_t)i0 * D))[c4];
            ax += __uint_as_float(v0.x << 16) * hm;
            ay += __uint_as_float(v0.x & 0xffff0000u) * hm;
            az += __uint_as_float(v0.y << 16) * hm;
            aw += __uint_as_float(v0.y & 0xffff0000u) * hm;
        }
        // merge odd-edge stream (high half) into low half
        ax += __shfl_down(ax, 32);
        ay += __shfl_down(ay, 32);
        az += __shfl_down(az, 32);
        aw += __shfl_down(aw, 32);
        if (half == 0) {
            float dv = dinv[node];
            float y0 = fmaxf(fmaf(ax, dv, b4.x), 0.f);
            float y1 = fmaxf(fmaf(ay, dv, b4.y), 0.f);
            float y2 = fmaxf(fmaf(az, dv, b4.z), 0.f);
            float y3 = fmaxf(fmaf(aw, dv, b4.w), 0.f);
            ((float4*)(y + (size_t)node * D))[c4] = make_float4(y0, y1, y2, y3);
            ps0 += y0; ps1 += y1; ps2 += y2; ps3 += y3;
            pq0 += y0 * y0; pq1 += y1 * y1; pq2 += y2 * y2; pq3 += y3 * y3;
        }
    }

    __shared__ float red_s[4][128];
    __shared__ float red_q[4][128];
    if (half == 0) {
        red_s[wv][c4 * 4 + 0] = ps0; red_s[wv][c4 * 4 + 1] = ps1;
        red_s[wv][c4 * 4 + 2] = ps2; red_s[wv][c4 * 4 + 3] = ps3;
        red_q[wv][c4 * 4 + 0] = pq0; red_q[wv][c4 * 4 + 1] = pq1;
        red_q[wv][c4 * 4 + 2] = pq2; red_q[wv][c4 * 4 + 3] = pq3;
    }
    __syncthreads();
    if (tid < 128) {
        float s = red_s[0][tid] + red_s[1][tid] + red_s[2][tid] + red_s[3][tid];
        atomicAdd(&bnacc[tid], s);
    } else {
        int c = tid - 128;
        float q = red_q[0][c] + red_q[1][c] + red_q[2][c] + red_q[3][c];
        atomicAdd(&bnacc[128 + c], q);
    }
}

// ---------------- BN finalize: per-column scale/shift ----------------
__global__ void k_bnfinal(const float* __restrict__ bnacc, const float* __restrict__ gamma,
                          const float* __restrict__ beta, float* __restrict__ scsh, int N) {
    int c = threadIdx.x;
    if (c < 128) {
        float invN = 1.0f / (float)N;
        float mean = bnacc[c] * invN;
        float var = bnacc[128 + c] * invN - mean * mean;
        var = fmaxf(var, 0.f);
        float sc = gamma[c] * rsqrtf(var + BN_EPS);
        scsh[c] = sc;
        scsh[128 + c] = beta[c] - mean * sc;
    }
}

// ---------------- normalize + dropout, in place on d_out ----------------
__global__ __launch_bounds__(256) void k_finalize(
    float* __restrict__ out, const float* __restrict__ u,
    const float* __restrict__ scsh, int total4) {
    int i = blockIdx.x * 256 + threadIdx.x;
    if (i >= total4) return;
    float4 v = ((const float4*)out)[i];
    float4 uu = ((const float4*)u)[i];
    int c = (i & 31) * 4;
    float s0 = scsh[c], s1 = scsh[c + 1], s2 = scsh[c + 2], s3 = scsh[c + 3];
    float h0 = scsh[128 + c], h1 = scsh[128 + c + 1];
    float h2 = scsh[128 + c + 2], h3 = scsh[128 + c + 3];
    v.x = fmaf(v.x, s0, h0) * (uu.x > P_DROP ? INV_KEEP : 0.f);
    v.y = fmaf(v.y, s1, h1) * (uu.y > P_DROP ? INV_KEEP : 0.f);
    v.z = fmaf(v.z, s2, h2) * (uu.z > P_DROP ? INV_KEEP : 0.f);
    v.w = fmaf(v.w, s3, h3) * (uu.w > P_DROP ? INV_KEEP : 0.f);
    ((float4*)out)[i] = v;
}

extern "C" void kernel_launch(void* const* d_in, const int* in_sizes, int n_in,
                              void* d_out, int out_size, void* d_ws, size_t ws_size,
                              hipStream_t stream) {
    const float* x      = (const float*)d_in[0];
    const float* weight = (const float*)d_in[1];
    const float* bias   = (const float*)d_in[2];
    const float* gamma  = (const float*)d_in[3];
    const float* beta   = (const float*)d_in[4];
    const float* du     = (const float*)d_in[5];
    const int*   eidx   = (const int*)d_in[6];
    float* out = (float*)d_out;

    const int N = in_sizes[0] / D;      // 50000
    const int E = in_sizes[6] / 2;      // 600000
    const int* esrc = eidx;
    const int* edst = eidx + E;

    char* p = (char*)d_ws;
    auto alloc = [&](size_t bytes) {
        char* q = p;
        p += (bytes + 255) & ~(size_t)255;
        return q;
    };
    unsigned short* xwb = (unsigned short*)alloc((size_t)N * D * sizeof(unsigned short));
    int*   hist     = (int*)alloc((size_t)N * sizeof(int));
    int*   cursor   = (int*)alloc((size_t)N * sizeof(int));
    int*   off      = (int*)alloc((size_t)(N + 1) * sizeof(int));
    const int NBLK = (N + 255) / 256;   // 196 (<=256 required by scanB)
    int*   tmp      = (int*)alloc((size_t)NBLK * 256 * sizeof(int));
    int*   blocksum = (int*)alloc((size_t)NBLK * sizeof(int));
    int*   blockoff = (int*)alloc((size_t)NBLK * sizeof(int));
    int*   ebuf     = (int*)alloc((size_t)E * sizeof(int));
    float* dinv     = (float*)alloc((size_t)N * sizeof(float));
    float* bnacc    = (float*)alloc(256 * sizeof(float));
    float* scsh     = (float*)alloc(256 * sizeof(float));

    const int EB = (E + 255) / 256;
    hipLaunchKernelGGL(k_init, dim3(NBLK), dim3(256), 0, stream, hist, bnacc, N);
    hipLaunchKernelGGL(k_hist, dim3(EB), dim3(256), 0, stream, edst, hist, E);
    hipLaunchKernelGGL(k_scanA, dim3(NBLK), dim3(256), 0, stream, hist, tmp, blocksum, N);
    hipLaunchKernelGGL(k_scanB, dim3(1), dim3(256), 0, stream, blocksum, blockoff, NBLK);
    hipLaunchKernelGGL(k_scanC, dim3(NBLK), dim3(256), 0, stream, tmp, blockoff, hist, off, cursor, N);
    hipLaunchKernelGGL(k_place, dim3(EB), dim3(256), 0, stream, esrc, edst, cursor, ebuf, E);
    hipLaunchKernelGGL(k_gemm, dim3((N + 63) / 64), dim3(256), 0, stream,
                       x, weight, hist, xwb, dinv, N);
    const int AGG_BLOCKS = 2048;
    hipLaunchKernelGGL(k_aggregate, dim3(AGG_BLOCKS), dim3(256), 0, stream,
                       xwb, dinv, off, ebuf, bias, out, bnacc, N, AGG_BLOCKS * 4);
    hipLaunchKernelGGL(k_bnfinal, dim3(1), dim3(128), 0, stream, bnacc, gamma, beta, scsh, N);
    const int total4 = N * (D / 4);
    hipLaunchKernelGGL(k_finalize, dim3((total4 + 255) / 256), dim3(256), 0, stream,
                       out, du, scsh, total4);
}

// Round 4
// 257.751 us; speedup vs baseline: 1.1397x; 1.0879x over previous
//
#include <hip/hip_runtime.h>
#include <cstdint>
#include <cstddef>

#define D 128
#define P_DROP 0.1f
#define INV_KEEP (1.0f / 0.9f)
#define BN_EPS 1e-5f

typedef __attribute__((ext_vector_type(8))) short bf16x8;
typedef __attribute__((ext_vector_type(4))) float f32x4;

// round-to-nearest-even f32 -> bf16 bits (inputs finite)
__device__ __forceinline__ unsigned f2bf(float f) {
    unsigned u = __float_as_uint(f);
    return (u + 0x7fffu + ((u >> 16) & 1u)) >> 16;
}
__device__ __forceinline__ float bf_lo(unsigned v) { return __uint_as_float(v << 16); }
__device__ __forceinline__ float bf_hi(unsigned v) { return __uint_as_float(v & 0xffff0000u); }

// ---------------- init: zero hist / bn accumulators ----------------
__global__ void k_init(int* __restrict__ hist, float* __restrict__ bnacc, int N) {
    int i = blockIdx.x * blockDim.x + threadIdx.x;
    if (i < N) hist[i] = 0;
    if (i < 256) bnacc[i] = 0.f;
}

// ---------------- histogram of dst ----------------
__global__ void k_hist(const int* __restrict__ dst, int* __restrict__ hist, int E) {
    int i = blockIdx.x * blockDim.x + threadIdx.x;
    if (i < E) atomicAdd(&hist[dst[i]], 1);
}

// ---------------- 2-level exclusive scan ----------------
__global__ void k_scanA(const int* __restrict__ hist, int* __restrict__ tmp,
                        int* __restrict__ blocksum, int N) {
    __shared__ int sd[256];
    int tid = threadIdx.x;
    int i = blockIdx.x * 256 + tid;
    sd[tid] = (i < N) ? hist[i] : 0;
    __syncthreads();
    for (int o = 1; o < 256; o <<= 1) {
        int t = (tid >= o) ? sd[tid - o] : 0;
        __syncthreads();
        sd[tid] += t;
        __syncthreads();
    }
    tmp[i] = sd[tid];
    if (tid == 255) blocksum[blockIdx.x] = sd[255];
}

__global__ void k_scanB(const int* __restrict__ blocksum, int* __restrict__ blockoff,
                        int NBLK) {
    __shared__ int sd[256];
    int tid = threadIdx.x;
    int v = (tid < NBLK) ? blocksum[tid] : 0;
    sd[tid] = v;
    __syncthreads();
    for (int o = 1; o < 256; o <<= 1) {
        int t = (tid >= o) ? sd[tid - o] : 0;
        __syncthreads();
        sd[tid] += t;
        __syncthreads();
    }
    if (tid < NBLK) blockoff[tid] = sd[tid] - v;
}

__global__ void k_scanC(const int* __restrict__ tmp, const int* __restrict__ blockoff,
                        const int* __restrict__ hist,
                        int* __restrict__ off, int* __restrict__ cursor, int N) {
    int i = blockIdx.x * 256 + threadIdx.x;
    if (i < N) {
        int incl = tmp[i] + blockoff[blockIdx.x];
        off[i + 1] = incl;
        cursor[i] = incl - hist[i];
    }
    if (i == 0) off[0] = 0;
}

// ---------------- CSR placement ----------------
__global__ void k_place(const int* __restrict__ src, const int* __restrict__ dst,
                        int* __restrict__ cursor, int* __restrict__ ebuf, int E) {
    int i = blockIdx.x * blockDim.x + threadIdx.x;
    if (i < E) {
        int p = atomicAdd(&cursor[dst[i]], 1);
        ebuf[p] = src[i];
    }
}

// ---------------- MFMA GEMM: xwb = bf16((x @ W) * rsqrt(deg)) ----------------
// block 256 thr (4 waves), 64-row tile. W transposed to LDS (k-contiguous),
// x tile bf16 row-major in LDS. mfma_f32_16x16x32_bf16:
//   A[m=lane&15][k=quad*8+j], B[k=quad*8+j][n=lane&15], D[m=quad*4+reg][n=lane&15]
__global__ __launch_bounds__(256) void k_gemm(
    const float* __restrict__ x, const float* __restrict__ w,
    const int* __restrict__ hist, unsigned short* __restrict__ xwb,
    float* __restrict__ dinv, int N) {
    __shared__ unsigned short xs[64][136];    // 17 KB
    __shared__ unsigned short wt[128][136];   // 34 KB  (wt[n][k])
    int tid = threadIdx.x;
    int row0 = blockIdx.x * 64;

    // stage W transposed (pairs along k): 64 kp x 128 n = 8192 pairs, 32/thread
#pragma unroll
    for (int i = 0; i < 32; ++i) {
        int flat = tid + i * 256;
        int n = flat & 127;
        int kp = flat >> 7;
        float a0 = w[(size_t)(2 * kp) * D + n];
        float a1 = w[(size_t)(2 * kp + 1) * D + n];
        *(unsigned*)&wt[n][2 * kp] = f2bf(a0) | (f2bf(a1) << 16);
    }
    // stage x tile: 64 rows x 32 float4 = 2048 quads, 8/thread
#pragma unroll
    for (int i = 0; i < 8; ++i) {
        int flat = tid + i * 256;
        int r = flat >> 5;
        int kq = flat & 31;
        int row = row0 + r;
        float4 v = (row < N) ? *(const float4*)&x[(size_t)row * D + kq * 4]
                             : make_float4(0.f, 0.f, 0.f, 0.f);
        uint2 pk;
        pk.x = f2bf(v.x) | (f2bf(v.y) << 16);
        pk.y = f2bf(v.z) | (f2bf(v.w) << 16);
        *(uint2*)&xs[r][kq * 4] = pk;
    }
    __syncthreads();

    int wv = tid >> 6, lane = tid & 63;
    int l15 = lane & 15, quad = lane >> 4;
    int mrow = wv * 16 + l15;
    f32x4 acc[8];
#pragma unroll
    for (int t = 0; t < 8; ++t) acc[t] = (f32x4){0.f, 0.f, 0.f, 0.f};
#pragma unroll
    for (int k0 = 0; k0 < D; k0 += 32) {
        bf16x8 af = *(bf16x8*)&xs[mrow][k0 + quad * 8];
#pragma unroll
        for (int nt = 0; nt < 8; ++nt) {
            bf16x8 bfr = *(bf16x8*)&wt[nt * 16 + l15][k0 + quad * 8];
            acc[nt] = __builtin_amdgcn_mfma_f32_16x16x32_bf16(af, bfr, acc[nt], 0, 0, 0);
        }
    }
    // epilogue: node = row0 + wv*16 + quad*4 + reg, col = nt*16 + l15
#pragma unroll
    for (int reg = 0; reg < 4; ++reg) {
        int node = row0 + wv * 16 + quad * 4 + reg;
        if (node < N) {
            float dv = rsqrtf((float)(hist[node] + 1));
            if (l15 == 0) dinv[node] = dv;
#pragma unroll
            for (int nt = 0; nt < 8; ++nt) {
                float val = acc[nt][reg] * dv;
                xwb[(size_t)node * D + nt * 16 + l15] = (unsigned short)f2bf(val);
            }
        }
    }
}

// ---------------- gather-aggregate + bias + ReLU + BN partials ----------------
// wave owns contiguous node run; off/dinv preloaded per run, indices per chunk,
// gathers issued in batches of 16 via wave-uniform (readlane) bases.
__global__ __launch_bounds__(256) void k_aggregate(
    const unsigned short* __restrict__ xwb, const float* __restrict__ dinv,
    const int* __restrict__ off, const int* __restrict__ ebuf,
    const float* __restrict__ bias, float* __restrict__ y,
    float* __restrict__ bnacc, int N, int nwaves) {
    int tid = threadIdx.x;
    int lane = tid & 63;
    int wv = tid >> 6;
    int gw = blockIdx.x * 4 + wv;
    int chunk = (N + nwaves - 1) / nwaves;      // <= 63
    int a = gw * chunk;
    int b = min(a + chunk, N);
    float2 b2 = ((const float2*)bias)[lane];    // cols {2lane, 2lane+1}
    float ps0 = 0.f, ps1 = 0.f, pq0 = 0.f, pq1 = 0.f;

    if (a < b) {
        int run = b - a;
        int v_off = off[a + min(lane, run)];                      // off[a..b]
        int v_dv  = ((const int*)dinv)[a + min(lane, run - 1)];   // dinv[a..b-1]
        for (int n = a; n < b; ++n) {
            int nl = n - a;
            int s0 = __builtin_amdgcn_readlane(v_off, nl);
            int s1 = __builtin_amdgcn_readlane(v_off, nl + 1);
            unsigned selfv = *(const unsigned*)(xwb + (size_t)n * D + lane * 2);
            float ax = bf_lo(selfv), ay = bf_hi(selfv);
            for (int c = s0; c < s1; c += 64) {
                int m = min(64, s1 - c);
                int vidx = ebuf[c + lane];      // coalesced (ebuf padded by 64)
                int e = 0;
                for (; e + 16 <= m; e += 16) {
                    unsigned vv[16];
#pragma unroll
                    for (int j = 0; j < 16; ++j) {
                        int idx = __builtin_amdgcn_readlane(vidx, e + j);
                        vv[j] = *(const unsigned*)(xwb + (size_t)idx * D + lane * 2);
                    }
#pragma unroll
                    for (int j = 0; j < 16; ++j) { ax += bf_lo(vv[j]); ay += bf_hi(vv[j]); }
                }
                for (; e + 4 <= m; e += 4) {
                    unsigned vv[4];
#pragma unroll
                    for (int j = 0; j < 4; ++j) {
                        int idx = __builtin_amdgcn_readlane(vidx, e + j);
                        vv[j] = *(const unsigned*)(xwb + (size_t)idx * D + lane * 2);
                    }
#pragma unroll
                    for (int j = 0; j < 4; ++j) { ax += bf_lo(vv[j]); ay += bf_hi(vv[j]); }
                }
                for (; e < m; ++e) {
                    int idx = __builtin_amdgcn_readlane(vidx, e);
                    unsigned v = *(const unsigned*)(xwb + (size_t)idx * D + lane * 2);
                    ax += bf_lo(v); ay += bf_hi(v);
                }
            }
            float dv = __int_as_float(__builtin_amdgcn_readlane(v_dv, nl));
            float y0 = fmaxf(fmaf(ax, dv, b2.x), 0.f);
            float y1 = fmaxf(fmaf(ay, dv, b2.y), 0.f);
            *(float2*)(y + (size_t)n * D + lane * 2) = make_float2(y0, y1);
            ps0 += y0; ps1 += y1;
            pq0 += y0 * y0; pq1 += y1 * y1;
        }
    }

    __shared__ float red[4][256];
    red[wv][lane * 2] = ps0;       red[wv][lane * 2 + 1] = ps1;
    red[wv][128 + lane * 2] = pq0; red[wv][128 + lane * 2 + 1] = pq1;
    __syncthreads();
    {
        float s = red[0][tid] + red[1][tid] + red[2][tid] + red[3][tid];
        atomicAdd(&bnacc[tid], s);
    }
}

// ---------------- BN finalize ----------------
__global__ void k_bnfinal(const float* __restrict__ bnacc, const float* __restrict__ gamma,
                          const float* __restrict__ beta, float* __restrict__ scsh, int N) {
    int c = threadIdx.x;
    if (c < 128) {
        float invN = 1.0f / (float)N;
        float mean = bnacc[c] * invN;
        float var = bnacc[128 + c] * invN - mean * mean;
        var = fmaxf(var, 0.f);
        float sc = gamma[c] * rsqrtf(var + BN_EPS);
        scsh[c] = sc;
        scsh[128 + c] = beta[c] - mean * sc;
    }
}

// ---------------- normalize + dropout, in place ----------------
__global__ __launch_bounds__(256) void k_finalize(
    float* __restrict__ out, const float* __restrict__ u,
    const float* __restrict__ scsh, int total4) {
    int i = blockIdx.x * 256 + threadIdx.x;
    if (i >= total4) return;
    float4 v = ((const float4*)out)[i];
    float4 uu = ((const float4*)u)[i];
    int c = (i & 31) * 4;
    float s0 = scsh[c], s1 = scsh[c + 1], s2 = scsh[c + 2], s3 = scsh[c + 3];
    float h0 = scsh[128 + c], h1 = scsh[128 + c + 1];
    float h2 = scsh[128 + c + 2], h3 = scsh[128 + c + 3];
    v.x = fmaf(v.x, s0, h0) * (uu.x > P_DROP ? INV_KEEP : 0.f);
    v.y = fmaf(v.y, s1, h1) * (uu.y > P_DROP ? INV_KEEP : 0.f);
    v.z = fmaf(v.z, s2, h2) * (uu.z > P_DROP ? INV_KEEP : 0.f);
    v.w = fmaf(v.w, s3, h3) * (uu.w > P_DROP ? INV_KEEP : 0.f);
    ((float4*)out)[i] = v;
}

extern "C" void kernel_launch(void* const* d_in, const int* in_sizes, int n_in,
                              void* d_out, int out_size, void* d_ws, size_t ws_size,
                              hipStream_t stream) {
    const float* x      = (const float*)d_in[0];
    const float* weight = (const float*)d_in[1];
    const float* bias   = (const float*)d_in[2];
    const float* gamma  = (const float*)d_in[3];
    const float* beta   = (const float*)d_in[4];
    const float* du     = (const float*)d_in[5];
    const int*   eidx   = (const int*)d_in[6];
    float* out = (float*)d_out;

    const int N = in_sizes[0] / D;      // 50000
    const int E = in_sizes[6] / 2;      // 600000
    const int* esrc = eidx;
    const int* edst = eidx + E;

    char* p = (char*)d_ws;
    auto alloc = [&](size_t bytes) {
        char* q = p;
        p += (bytes + 255) & ~(size_t)255;
        return q;
    };
    unsigned short* xwb = (unsigned short*)alloc((size_t)N * D * sizeof(unsigned short));
    int*   hist     = (int*)alloc((size_t)N * sizeof(int));
    int*   cursor   = (int*)alloc((size_t)N * sizeof(int));
    int*   off      = (int*)alloc((size_t)(N + 1) * sizeof(int));
    const int NBLK = (N + 255) / 256;   // 196
    int*   tmp      = (int*)alloc((size_t)NBLK * 256 * sizeof(int));
    int*   blocksum = (int*)alloc((size_t)NBLK * sizeof(int));
    int*   blockoff = (int*)alloc((size_t)NBLK * sizeof(int));
    int*   ebuf     = (int*)alloc((size_t)(E + 64) * sizeof(int));  // +64 pad for OOB-safe chunk loads
    float* dinv     = (float*)alloc((size_t)N * sizeof(float));
    float* bnacc    = (float*)alloc(256 * sizeof(float));
    float* scsh     = (float*)alloc(256 * sizeof(float));

    const int EB = (E + 255) / 256;
    hipLaunchKernelGGL(k_init, dim3(NBLK), dim3(256), 0, stream, hist, bnacc, N);
    hipLaunchKernelGGL(k_hist, dim3(EB), dim3(256), 0, stream, edst, hist, E);
    hipLaunchKernelGGL(k_scanA, dim3(NBLK), dim3(256), 0, stream, hist, tmp, blocksum, N);
    hipLaunchKernelGGL(k_scanB, dim3(1), dim3(256), 0, stream, blocksum, blockoff, NBLK);
    hipLaunchKernelGGL(k_scanC, dim3(NBLK), dim3(256), 0, stream, tmp, blockoff, hist, off, cursor, N);
    hipLaunchKernelGGL(k_place, dim3(EB), dim3(256), 0, stream, esrc, edst, cursor, ebuf, E);
    hipLaunchKernelGGL(k_gemm, dim3((N + 63) / 64), dim3(256), 0, stream,
                       x, weight, hist, xwb, dinv, N);
    const int AGG_BLOCKS = 2048;
    hipLaunchKernelGGL(k_aggregate, dim3(AGG_BLOCKS), dim3(256), 0, stream,
                       xwb, dinv, off, ebuf, bias, out, bnacc, N, AGG_BLOCKS * 4);
    hipLaunchKernelGGL(k_bnfinal, dim3(1), dim3(128), 0, stream, bnacc, gamma, beta, scsh, N);
    const int total4 = N * (D / 4);
    hipLaunchKernelGGL(k_finalize, dim3((total4 + 255) / 256), dim3(256), 0, stream,
                       out, du, scsh, total4);
}

// Round 5
// 257.445 us; speedup vs baseline: 1.1410x; 1.0012x over previous
//
#include <hip/hip_runtime.h>
#include <cstdint>
#include <cstddef>

#define D 128
#define P_DROP 0.1f
#define INV_KEEP (1.0f / 0.9f)
#define BN_EPS 1e-5f

typedef __attribute__((ext_vector_type(8))) short bf16x8;
typedef __attribute__((ext_vector_type(4))) float f32x4;

__device__ __forceinline__ unsigned f2bf(float f) {
    unsigned u = __float_as_uint(f);
    return (u + 0x7fffu + ((u >> 16) & 1u)) >> 16;
}
__device__ __forceinline__ float bf_lo(unsigned v) { return __uint_as_float(v << 16); }
__device__ __forceinline__ float bf_hi(unsigned v) { return __uint_as_float(v & 0xffff0000u); }

// ---------------- init: zero y, hist, bnacc; write edge-array pads ----------------
__global__ void k_init(float4* __restrict__ y4, int n4,
                       int* __restrict__ hist, int N,
                       float* __restrict__ bnacc,
                       int* __restrict__ ssrc, int* __restrict__ sdst, int E) {
    int stride = gridDim.x * blockDim.x;
    int i0 = blockIdx.x * blockDim.x + threadIdx.x;
    float4 z = make_float4(0.f, 0.f, 0.f, 0.f);
    for (int i = i0; i < n4; i += stride) y4[i] = z;
    for (int i = i0; i < N; i += stride) hist[i] = 0;
    if (i0 < 256) bnacc[i0] = 0.f;
    if (i0 < 64) { ssrc[E + i0] = 0; sdst[E + i0] = -1; }   // sentinel pad
}

// ---------------- histogram of dst ----------------
__global__ void k_hist(const int* __restrict__ dst, int* __restrict__ hist, int E) {
    int i = blockIdx.x * blockDim.x + threadIdx.x;
    if (i < E) atomicAdd(&hist[dst[i]], 1);
}

// ---------------- 2-level exclusive scan ----------------
__global__ void k_scanA(const int* __restrict__ hist, int* __restrict__ tmp,
                        int* __restrict__ blocksum, int N) {
    __shared__ int sd[256];
    int tid = threadIdx.x;
    int i = blockIdx.x * 256 + tid;
    sd[tid] = (i < N) ? hist[i] : 0;
    __syncthreads();
    for (int o = 1; o < 256; o <<= 1) {
        int t = (tid >= o) ? sd[tid - o] : 0;
        __syncthreads();
        sd[tid] += t;
        __syncthreads();
    }
    tmp[i] = sd[tid];
    if (tid == 255) blocksum[blockIdx.x] = sd[255];
}

__global__ void k_scanB(const int* __restrict__ blocksum, int* __restrict__ blockoff,
                        int NBLK) {
    __shared__ int sd[256];
    int tid = threadIdx.x;
    int v = (tid < NBLK) ? blocksum[tid] : 0;
    sd[tid] = v;
    __syncthreads();
    for (int o = 1; o < 256; o <<= 1) {
        int t = (tid >= o) ? sd[tid - o] : 0;
        __syncthreads();
        sd[tid] += t;
        __syncthreads();
    }
    if (tid < NBLK) blockoff[tid] = sd[tid] - v;
}

// cursor[i] = exclusive scan (live write index for place)
__global__ void k_scanC(const int* __restrict__ tmp, const int* __restrict__ blockoff,
                        const int* __restrict__ hist, int* __restrict__ cursor, int N) {
    int i = blockIdx.x * 256 + threadIdx.x;
    if (i < N) cursor[i] = tmp[i] + blockoff[blockIdx.x] - hist[i];
}

// ---------------- placement: dst-sorted (src,dst) arrays ----------------
__global__ void k_place(const int* __restrict__ src, const int* __restrict__ dst,
                        int* __restrict__ cursor,
                        int* __restrict__ ssrc, int* __restrict__ sdst, int E) {
    int i = blockIdx.x * blockDim.x + threadIdx.x;
    if (i < E) {
        int d = dst[i];
        int p = atomicAdd(&cursor[d], 1);
        ssrc[p] = src[i];
        sdst[p] = d;
    }
}

// ---------------- MFMA GEMM: xwb = bf16((x @ W) * rsqrt(deg)) ----------------
__global__ __launch_bounds__(256) void k_gemm(
    const float* __restrict__ x, const float* __restrict__ w,
    const int* __restrict__ hist, unsigned short* __restrict__ xwb,
    float* __restrict__ dinv, int N) {
    __shared__ unsigned short xs[64][136];
    __shared__ unsigned short wt[128][136];
    int tid = threadIdx.x;
    int row0 = blockIdx.x * 64;

#pragma unroll
    for (int i = 0; i < 32; ++i) {
        int flat = tid + i * 256;
        int n = flat & 127;
        int kp = flat >> 7;
        float a0 = w[(size_t)(2 * kp) * D + n];
        float a1 = w[(size_t)(2 * kp + 1) * D + n];
        *(unsigned*)&wt[n][2 * kp] = f2bf(a0) | (f2bf(a1) << 16);
    }
#pragma unroll
    for (int i = 0; i < 8; ++i) {
        int flat = tid + i * 256;
        int r = flat >> 5;
        int kq = flat & 31;
        int row = row0 + r;
        float4 v = (row < N) ? *(const float4*)&x[(size_t)row * D + kq * 4]
                             : make_float4(0.f, 0.f, 0.f, 0.f);
        uint2 pk;
        pk.x = f2bf(v.x) | (f2bf(v.y) << 16);
        pk.y = f2bf(v.z) | (f2bf(v.w) << 16);
        *(uint2*)&xs[r][kq * 4] = pk;
    }
    __syncthreads();

    int wv = tid >> 6, lane = tid & 63;
    int l15 = lane & 15, quad = lane >> 4;
    int mrow = wv * 16 + l15;
    f32x4 acc[8];
#pragma unroll
    for (int t = 0; t < 8; ++t) acc[t] = (f32x4){0.f, 0.f, 0.f, 0.f};
#pragma unroll
    for (int k0 = 0; k0 < D; k0 += 32) {
        bf16x8 af = *(bf16x8*)&xs[mrow][k0 + quad * 8];
#pragma unroll
        for (int nt = 0; nt < 8; ++nt) {
            bf16x8 bfr = *(bf16x8*)&wt[nt * 16 + l15][k0 + quad * 8];
            acc[nt] = __builtin_amdgcn_mfma_f32_16x16x32_bf16(af, bfr, acc[nt], 0, 0, 0);
        }
    }
#pragma unroll
    for (int reg = 0; reg < 4; ++reg) {
        int node = row0 + wv * 16 + quad * 4 + reg;
        if (node < N) {
            float dv = rsqrtf((float)(hist[node] + 1));
            if (l15 == 0) dinv[node] = dv;
#pragma unroll
            for (int nt = 0; nt < 8; ++nt) {
                float val = acc[nt][reg] * dv;
                xwb[(size_t)node * D + nt * 16 + l15] = (unsigned short)f2bf(val);
            }
        }
    }
}

// ---------------- edge-parallel gather with flush-on-dst-change ----------------
// wave owns 64 sorted edges; lane covers cols {2l,2l+1}; 32 row-loads in flight;
// interior segments direct-store, wave-boundary segments atomicAdd.
__global__ __launch_bounds__(256) void k_aggregate(
    const unsigned short* __restrict__ xwb, const float* __restrict__ dinv,
    const int* __restrict__ ssrc, const int* __restrict__ sdst,
    float* __restrict__ y, int E) {
    int lane = threadIdx.x & 63;
    int wv = threadIdx.x >> 6;
    int w = blockIdx.x * 4 + wv;
    int e0 = w * 64;
    if (e0 >= E) return;

    int vsrc = ssrc[e0 + lane];
    int vdst = sdst[e0 + lane];
    int prevd = (w > 0) ? __builtin_amdgcn_readfirstlane(sdst[e0 - 1]) : -5;
    int nextd = __builtin_amdgcn_readfirstlane(sdst[e0 + 64]);   // pad-safe
    int cidx = vdst < 0 ? 0 : vdst;
    float dvv = dinv[cidx];                     // per-lane gather of dinv[dst]

    float a0 = 0.f, a1 = 0.f;
    int cur = __builtin_amdgcn_readlane(vdst, 0);
    bool excl = (prevd != cur);

    unsigned vrow[32];
#pragma unroll
    for (int half = 0; half < 2; ++half) {
        int base = half * 32;
#pragma unroll
        for (int j = 0; j < 32; ++j) {
            int idx = __builtin_amdgcn_readlane(vsrc, base + j);
            vrow[j] = *(const unsigned*)(xwb + (size_t)idx * D + lane * 2);
        }
#pragma unroll
        for (int j = 0; j < 32; ++j) {
            int gj = base + j;
            int dj = __builtin_amdgcn_readlane(vdst, gj);
            if (dj != cur) {
                // flush segment `cur` (ended at gj-1)
                float dv = __int_as_float(
                    __builtin_amdgcn_readlane(__float_as_int(dvv), gj - 1));
                float s0 = a0 * dv, s1 = a1 * dv;
                float* yp = y + (size_t)cur * D + lane * 2;
                if (excl) { *(float2*)yp = make_float2(s0, s1); }
                else { atomicAdd(yp, s0); atomicAdd(yp + 1, s1); }
                a0 = 0.f; a1 = 0.f; cur = dj; excl = true;
            }
            unsigned v = vrow[j];
            a0 += bf_lo(v); a1 += bf_hi(v);
        }
    }
    if (cur >= 0) {
        float dv = __int_as_float(__builtin_amdgcn_readlane(__float_as_int(dvv), 63));
        float s0 = a0 * dv, s1 = a1 * dv;
        float* yp = y + (size_t)cur * D + lane * 2;
        if (excl && (nextd != cur)) { *(float2*)yp = make_float2(s0, s1); }
        else { atomicAdd(yp, s0); atomicAdd(yp + 1, s1); }
    }
}

// ---------------- post-aggregate: + self + bias, ReLU, BN partials ----------------
__global__ __launch_bounds__(256) void k_postagg(
    float* __restrict__ y, const unsigned short* __restrict__ xwb,
    const float* __restrict__ dinv, const float* __restrict__ bias,
    float* __restrict__ bnacc, int total4) {
    int tid = threadIdx.x;
    int stride = gridDim.x * 256;
    int c4 = tid & 31;
    float4 b4 = ((const float4*)bias)[c4];
    float s0 = 0.f, s1 = 0.f, s2 = 0.f, s3 = 0.f;
    float q0 = 0.f, q1 = 0.f, q2 = 0.f, q3 = 0.f;
    for (int i = blockIdx.x * 256 + tid; i < total4; i += stride) {
        int node = i >> 5;
        float4 z = ((float4*)y)[i];
        uint2 sv = *(const uint2*)(xwb + (size_t)node * D + c4 * 4);
        float dv = dinv[node];
        z.x = fmaxf(fmaf(bf_lo(sv.x), dv, z.x) + b4.x, 0.f);
        z.y = fmaxf(fmaf(bf_hi(sv.x), dv, z.y) + b4.y, 0.f);
        z.z = fmaxf(fmaf(bf_lo(sv.y), dv, z.z) + b4.z, 0.f);
        z.w = fmaxf(fmaf(bf_hi(sv.y), dv, z.w) + b4.w, 0.f);
        ((float4*)y)[i] = z;
        s0 += z.x; s1 += z.y; s2 += z.z; s3 += z.w;
        q0 += z.x * z.x; q1 += z.y * z.y; q2 += z.z * z.z; q3 += z.w * z.w;
    }
    __shared__ float red[256][8];
    red[tid][0] = s0; red[tid][1] = s1; red[tid][2] = s2; red[tid][3] = s3;
    red[tid][4] = q0; red[tid][5] = q1; red[tid][6] = q2; red[tid][7] = q3;
    __syncthreads();
    if (tid < 128) {
        int r0 = tid >> 2, sl = tid & 3;
        float acc = 0.f;
#pragma unroll
        for (int m = 0; m < 8; ++m) acc += red[r0 + 32 * m][sl];
        atomicAdd(&bnacc[tid], acc);
    } else {
        int t = tid - 128;
        int r0 = t >> 2, sl = 4 + (t & 3);
        float acc = 0.f;
#pragma unroll
        for (int m = 0; m < 8; ++m) acc += red[r0 + 32 * m][sl];
        atomicAdd(&bnacc[128 + t], acc);
    }
}

// ---------------- BN finalize ----------------
__global__ void k_bnfinal(const float* __restrict__ bnacc, const float* __restrict__ gamma,
                          const float* __restrict__ beta, float* __restrict__ scsh, int N) {
    int c = threadIdx.x;
    if (c < 128) {
        float invN = 1.0f / (float)N;
        float mean = bnacc[c] * invN;
        float var = bnacc[128 + c] * invN - mean * mean;
        var = fmaxf(var, 0.f);
        float sc = gamma[c] * rsqrtf(var + BN_EPS);
        scsh[c] = sc;
        scsh[128 + c] = beta[c] - mean * sc;
    }
}

// ---------------- normalize + dropout, in place ----------------
__global__ __launch_bounds__(256) void k_finalize(
    float* __restrict__ out, const float* __restrict__ u,
    const float* __restrict__ scsh, int total4) {
    int i = blockIdx.x * 256 + threadIdx.x;
    if (i >= total4) return;
    float4 v = ((const float4*)out)[i];
    float4 uu = ((const float4*)u)[i];
    int c = (i & 31) * 4;
    float s0 = scsh[c], s1 = scsh[c + 1], s2 = scsh[c + 2], s3 = scsh[c + 3];
    float h0 = scsh[128 + c], h1 = scsh[128 + c + 1];
    float h2 = scsh[128 + c + 2], h3 = scsh[128 + c + 3];
    v.x = fmaf(v.x, s0, h0) * (uu.x > P_DROP ? INV_KEEP : 0.f);
    v.y = fmaf(v.y, s1, h1) * (uu.y > P_DROP ? INV_KEEP : 0.f);
    v.z = fmaf(v.z, s2, h2) * (uu.z > P_DROP ? INV_KEEP : 0.f);
    v.w = fmaf(v.w, s3, h3) * (uu.w > P_DROP ? INV_KEEP : 0.f);
    ((float4*)out)[i] = v;
}

extern "C" void kernel_launch(void* const* d_in, const int* in_sizes, int n_in,
                              void* d_out, int out_size, void* d_ws, size_t ws_size,
                              hipStream_t stream) {
    const float* x      = (const float*)d_in[0];
    const float* weight = (const float*)d_in[1];
    const float* bias   = (const float*)d_in[2];
    const float* gamma  = (const float*)d_in[3];
    const float* beta   = (const float*)d_in[4];
    const float* du     = (const float*)d_in[5];
    const int*   eidx   = (const int*)d_in[6];
    float* out = (float*)d_out;

    const int N = in_sizes[0] / D;      // 50000
    const int E = in_sizes[6] / 2;      // 600000
    const int* esrc = eidx;
    const int* edst = eidx + E;

    char* p = (char*)d_ws;
    auto alloc = [&](size_t bytes) {
        char* q = p;
        p += (bytes + 255) & ~(size_t)255;
        return q;
    };
    unsigned short* xwb = (unsigned short*)alloc((size_t)N * D * sizeof(unsigned short));
    int*   hist     = (int*)alloc((size_t)N * sizeof(int));
    int*   cursor   = (int*)alloc((size_t)N * sizeof(int));
    const int NBLK = (N + 255) / 256;   // 196
    int*   tmp      = (int*)alloc((size_t)NBLK * 256 * sizeof(int));
    int*   blocksum = (int*)alloc((size_t)NBLK * sizeof(int));
    int*   blockoff = (int*)alloc((size_t)NBLK * sizeof(int));
    int*   ssrc     = (int*)alloc((size_t)(E + 64) * sizeof(int));
    int*   sdst     = (int*)alloc((size_t)(E + 64) * sizeof(int));
    float* dinv     = (float*)alloc((size_t)N * sizeof(float));
    float* bnacc    = (float*)alloc(256 * sizeof(float));
    float* scsh     = (float*)alloc(256 * sizeof(float));

    const int EB = (E + 255) / 256;
    const int total4 = N * (D / 4);
    hipLaunchKernelGGL(k_init, dim3(1024), dim3(256), 0, stream,
                       (float4*)out, total4, hist, N, bnacc, ssrc, sdst, E);
    hipLaunchKernelGGL(k_hist, dim3(EB), dim3(256), 0, stream, edst, hist, E);
    hipLaunchKernelGGL(k_scanA, dim3(NBLK), dim3(256), 0, stream, hist, tmp, blocksum, N);
    hipLaunchKernelGGL(k_scanB, dim3(1), dim3(256), 0, stream, blocksum, blockoff, NBLK);
    hipLaunchKernelGGL(k_scanC, dim3(NBLK), dim3(256), 0, stream, tmp, blockoff, hist, cursor, N);
    hipLaunchKernelGGL(k_place, dim3(EB), dim3(256), 0, stream, esrc, edst, cursor, ssrc, sdst, E);
    hipLaunchKernelGGL(k_gemm, dim3((N + 63) / 64), dim3(256), 0, stream,
                       x, weight, hist, xwb, dinv, N);
    const int NWAVE = (E + 63) / 64;            // 9375
    hipLaunchKernelGGL(k_aggregate, dim3((NWAVE + 3) / 4), dim3(256), 0, stream,
                       xwb, dinv, ssrc, sdst, out, E);
    hipLaunchKernelGGL(k_postagg, dim3(1024), dim3(256), 0, stream,
                       out, xwb, dinv, bias, bnacc, total4);
    hipLaunchKernelGGL(k_bnfinal, dim3(1), dim3(128), 0, stream, bnacc, gamma, beta, scsh, N);
    hipLaunchKernelGGL(k_finalize, dim3((total4 + 255) / 256), dim3(256), 0, stream,
                       out, du, scsh, total4);
}